// Round 12
// baseline (233.712 us; speedup 1.0000x reference)
//
#include <hip/hip_runtime.h>
#include <stdint.h>

// ---- problem constants ----
#define DIM    512
#define DSTATE 16
#define DINNER 1024
#define DTRANK 32
#define BB     2
#define LL     2048
#define NTOK   (BB*LL)      // 4096
#define NCHUNK 64
#define CLEN   (LL/NCHUNK)  // 32
#define NP     8            // x_proj K-split partials
#define LOG2E  1.4426950408889634f

typedef __bf16 bf16;
typedef bf16  bf16x8 __attribute__((ext_vector_type(8)));
typedef bf16  bf16x2 __attribute__((ext_vector_type(2)));
typedef float f32x4  __attribute__((ext_vector_type(4)));

// I/O dtype: FP32 (proven r3..r11). Internals: bf16.
// Perf ledger: r11=222.1 best. Model (confirmed r9/r10/r11): dispatch count is
// free; kernel work moves dur 1:1; ~160us is fixed harness cost (256MiB ws
// re-poison ~44us + restores + replay). This round: 1-barrier ping-pong GEMM
// staging + exp2 scans.

static __device__ __forceinline__ bf16x8 cvt8(const float* p)
{
    f32x4 a = *(const f32x4*)p, b = *(const f32x4*)(p + 4);
    bf16x8 o;
#pragma unroll
    for (int i = 0; i < 4; i++) { o[i] = (bf16)a[i]; o[4 + i] = (bf16)b[i]; }
    return o;
}

// async global->LDS, 16B per lane; LDS dest = wave-uniform base + lane*16 [m97]
static __device__ __forceinline__ void gload_lds16(const bf16* g, bf16* l)
{
    __builtin_amdgcn_global_load_lds(
        (const __attribute__((address_space(1))) void*)g,
        (__attribute__((address_space(3))) void*)l, 16, 0, 0);
}

// ---- bf16 weight shadow ----
#define WIN_N  (2*DINNER*DIM)          // 1,048,576
#define WX_N   (64*DINNER)             // 65,536
#define WOUT_N (DIM*DINNER)            // 524,288
#define WCVT_BLOCKS 800                // (WIN_N+WX_N+WOUT_N)/(256*8)
#define LN_BLOCKS   (NTOK/4)           // 1024

// ---------------------------------------------------------------------------
// prep: [0,800) weight cvt | [800,1824) LayerNorm
// ---------------------------------------------------------------------------
__global__ __launch_bounds__(256) void prep_kernel(const float* __restrict__ win,
                                                   const float* __restrict__ wx,
                                                   const float* __restrict__ wout,
                                                   bf16* __restrict__ wb,
                                                   const float* __restrict__ x,
                                                   const float* __restrict__ gamma,
                                                   const float* __restrict__ beta,
                                                   bf16* __restrict__ h)
{
    if (blockIdx.x < WCVT_BLOCKS) {
        int i = (blockIdx.x * 256 + threadIdx.x) * 8;
        const float* s; int j; bf16* dpt;
        if      (i < WIN_N)        { s = win;  j = i;                 dpt = wb; }
        else if (i < WIN_N + WX_N) { s = wx;   j = i - WIN_N;         dpt = wb + WIN_N; }
        else                       { s = wout; j = i - WIN_N - WX_N;  dpt = wb + WIN_N + WX_N; }
        *(bf16x8*)&dpt[j] = cvt8(&s[j]);
        return;
    }
    int bid = blockIdx.x - WCVT_BLOCKS;
    int w = threadIdx.x >> 6, lane = threadIdx.x & 63;
    int token = bid * 4 + w;
    const float* xr = x + (size_t)token * DIM + lane * 8;
    f32x4 va = *(const f32x4*)xr, vb = *(const f32x4*)(xr + 4);
    float vals[8];
#pragma unroll
    for (int i = 0; i < 4; i++) { vals[i] = va[i]; vals[4 + i] = vb[i]; }
    float s = 0.f;
#pragma unroll
    for (int i = 0; i < 8; i++) s += vals[i];
#pragma unroll
    for (int off = 32; off > 0; off >>= 1) s += __shfl_xor(s, off);
    float mean = s * (1.f / DIM);
    float vs = 0.f;
#pragma unroll
    for (int i = 0; i < 8; i++) { float d = vals[i] - mean; vs += d * d; }
#pragma unroll
    for (int off = 32; off > 0; off >>= 1) vs += __shfl_xor(vs, off);
    float rstd = rsqrtf(vs * (1.f / DIM) + 1e-5f);
    f32x4 ga = *(const f32x4*)(gamma + lane * 8), gb = *(const f32x4*)(gamma + lane * 8 + 4);
    f32x4 ba = *(const f32x4*)(beta + lane * 8),  bb = *(const f32x4*)(beta + lane * 8 + 4);
    bf16x8 o;
#pragma unroll
    for (int i = 0; i < 4; i++) {
        o[i]     = (bf16)((vals[i]     - mean) * rstd * ga[i] + ba[i]);
        o[4 + i] = (bf16)((vals[4 + i] - mean) * rstd * gb[i] + bb[i]);
    }
    *(bf16x8*)(h + (size_t)token * DIM + lane * 8) = o;
}

// ---------------------------------------------------------------------------
// Tiled MFMA GEMM with ping-pong LDS double-buffer (ONE barrier per K-iter;
// next tile's global_load_lds issues before this iter's MFMA, so its vmcnt
// drain lands at the NEXT barrier -> a full MFMA stage of load flight time).
// Safety: stage(i+1) writes the buffer last read at iter i-1; every thread's
// read(i-1) precedes barrier(i), every stage(i+1) follows barrier(i+... ) --
// one barrier separates them (see r12 journal).
// C[M,N] = A[M,K(lda)] * W[N,K(ldb)]^T.
// EPI: 0 = store bf16, 1 = fp32 partial store Cout[z][M][N], 2 = fp32 resid+store
// ---------------------------------------------------------------------------
template<int BM, int BN, int TM, int TN, int EPI>
__global__ __launch_bounds__(256) void gemm_kernel(const bf16* __restrict__ A, int lda,
                                                   const bf16* __restrict__ Bw, int ldb,
                                                   void* __restrict__ Cout,
                                                   const float* __restrict__ resid,
                                                   int M, int N, int K,
                                                   int kStart, int kLen)
{
    constexpr int WCols = BN / (TN * 16);
    constexpr int WRows = 4 / WCols;
    static_assert(WRows * TM * 16 == BM, "tile mismatch");
    __shared__ __align__(16) bf16 lsA[2][BM * 32];
    __shared__ __align__(16) bf16 lsB[2][BN * 32];
    const int tid  = threadIdx.x;
    const int lane = tid & 63;
    const int w    = tid >> 6;
    const int wr = w / WCols, wc = w % WCols;
    const int fr = lane & 15, q = lane >> 4;
    const int m0 = blockIdx.y * BM, n0 = blockIdx.x * BN;
    const int ks = kStart + blockIdx.z * kLen;

    f32x4 acc[TM][TN];
#pragma unroll
    for (int i = 0; i < TM; i++)
#pragma unroll
        for (int j = 0; j < TN; j++) acc[i][j] = (f32x4){0.f, 0.f, 0.f, 0.f};

    constexpr int NCA = (BM * 4) / 256;
    constexpr int NCB = (BN * 4) / 256;

    // prologue: stage first tile into buffer 0
#pragma unroll
    for (int c = 0; c < NCA; c++) {
        int lin = tid + c * 256;
        gload_lds16(&A[(size_t)(m0 + (lin >> 2)) * lda + ks + (lin & 3) * 8], &lsA[0][lin * 8]);
    }
#pragma unroll
    for (int c = 0; c < NCB; c++) {
        int lin = tid + c * 256;
        gload_lds16(&Bw[(size_t)(n0 + (lin >> 2)) * ldb + ks + (lin & 3) * 8], &lsB[0][lin * 8]);
    }

    int p = 0;
    for (int k0 = ks; k0 < ks + kLen; k0 += 32) {
        __syncthreads();   // buf[p] staged (compiler drains vmcnt here)
        if (k0 + 32 < ks + kLen) {   // prefetch next tile into buf[p^1]
#pragma unroll
            for (int c = 0; c < NCA; c++) {
                int lin = tid + c * 256;
                gload_lds16(&A[(size_t)(m0 + (lin >> 2)) * lda + k0 + 32 + (lin & 3) * 8],
                            &lsA[p ^ 1][lin * 8]);
            }
#pragma unroll
            for (int c = 0; c < NCB; c++) {
                int lin = tid + c * 256;
                gload_lds16(&Bw[(size_t)(n0 + (lin >> 2)) * ldb + k0 + 32 + (lin & 3) * 8],
                            &lsB[p ^ 1][lin * 8]);
            }
        }
        bf16x8 af[TM], bfr[TN];
#pragma unroll
        for (int i = 0; i < TM; i++)
            af[i] = *(const bf16x8*)&lsA[p][(wr * TM * 16 + i * 16 + fr) * 32 + q * 8];
#pragma unroll
        for (int j = 0; j < TN; j++)
            bfr[j] = *(const bf16x8*)&lsB[p][(wc * TN * 16 + j * 16 + fr) * 32 + q * 8];
#pragma unroll
        for (int i = 0; i < TM; i++)
#pragma unroll
            for (int j = 0; j < TN; j++)
                acc[i][j] = __builtin_amdgcn_mfma_f32_16x16x32_bf16(af[i], bfr[j], acc[i][j], 0, 0, 0);
        p ^= 1;
    }

    // epilogue: D[m][n] -> col = lane&15, row = (lane>>4)*4 + r  [m89/m91]
#pragma unroll
    for (int i = 0; i < TM; i++) {
#pragma unroll
        for (int j = 0; j < TN; j++) {
#pragma unroll
            for (int r = 0; r < 4; r++) {
                int row = m0 + wr * TM * 16 + i * 16 + q * 4 + r;
                int col = n0 + wc * TN * 16 + j * 16 + fr;
                float v = acc[i][j][r];
                if (EPI == 0) {
                    ((bf16*)Cout)[(size_t)row * N + col] = (bf16)v;
                } else if (EPI == 1) {
                    ((float*)Cout)[((size_t)blockIdx.z * M + row) * N + col] = v;
                } else {
                    size_t idx = (size_t)row * N + col;
                    ((float*)Cout)[idx] = resid[idx] + v;
                }
            }
        }
    }
}

// ---------------------------------------------------------------------------
// Depthwise causal conv (taps=4) + bias + SiLU. 8 channels/thread, bf16x8 I/O.
// ---------------------------------------------------------------------------
__global__ __launch_bounds__(256) void conv_kernel(const bf16* __restrict__ xz,
                                                   const float* __restrict__ cw,
                                                   const float* __restrict__ cb,
                                                   bf16* __restrict__ uact)
{
    int idx = blockIdx.x * 256 + threadIdx.x;   // NTOK * 128
    int c   = (idx & 127) * 8;
    int tok = idx >> 7;
    int b = tok >> 11, l = tok & 2047;
    float a[8];
    {
        f32x4 c0 = *(const f32x4*)&cb[c], c1 = *(const f32x4*)&cb[c + 4];
#pragma unroll
        for (int j = 0; j < 4; j++) { a[j] = c0[j]; a[4 + j] = c1[j]; }
    }
    float wv[8][4];
#pragma unroll
    for (int j = 0; j < 8; j++) {
        f32x4 wq = *(const f32x4*)&cw[(c + j) * 4];
#pragma unroll
        for (int k = 0; k < 4; k++) wv[j][k] = wq[k];
    }
#pragma unroll
    for (int k = 0; k < 4; k++) {
        int ls = l - 3 + k;
        if (ls >= 0) {
            bf16x8 uv = *(const bf16x8*)&xz[((size_t)(b * LL + ls)) * (2 * DINNER) + c];
#pragma unroll
            for (int j = 0; j < 8; j++) a[j] += (float)uv[j] * wv[j][k];
        }
    }
    bf16x8 o;
#pragma unroll
    for (int j = 0; j < 8; j++) {
        float v = a[j] / (1.f + __expf(-a[j]));
        o[j] = (bf16)v;
    }
    *(bf16x8*)&uact[(size_t)tok * DINNER + c] = o;
}

static __device__ __forceinline__ float softplusf(float v)
{
    return (v > 20.f) ? v : __logf(1.f + __expf(v));
}

// ---------------------------------------------------------------------------
// delta = softplus(dt @ dt_proj_w^T + b): one 16x16x32 MFMA per wave (K=32).
// A-fragment = sum of NP x_dbl partials (fp32), converted to bf16.
// ---------------------------------------------------------------------------
__global__ __launch_bounds__(256) void delta_kernel(const float* __restrict__ xdblp,
                                                    const float* __restrict__ dtw,
                                                    const float* __restrict__ dtb,
                                                    bf16* __restrict__ delta)
{
    int w = threadIdx.x >> 6, lane = threadIdx.x & 63;
    int tile = blockIdx.x * 4 + w;      // 256 x 64 tiles
    int tm = tile >> 6, tn = tile & 63;
    int fr = lane & 15, q = lane >> 4;
    int row_a = tm * 16 + fr;
    f32x4 s0 = (f32x4){0.f, 0.f, 0.f, 0.f}, s1 = s0;
#pragma unroll
    for (int p = 0; p < NP; p++) {
        const float* rp = &xdblp[((size_t)p * NTOK + row_a) * 64 + q * 8];
        s0 += *(const f32x4*)rp;
        s1 += *(const f32x4*)(rp + 4);
    }
    bf16x8 a;
#pragma unroll
    for (int i = 0; i < 4; i++) { a[i] = (bf16)s0[i]; a[4 + i] = (bf16)s1[i]; }
    bf16x8 b = cvt8(&dtw[(size_t)(tn * 16 + fr) * 32 + q * 8]);
    f32x4 acc = (f32x4){0.f, 0.f, 0.f, 0.f};
    acc = __builtin_amdgcn_mfma_f32_16x16x32_bf16(a, b, acc, 0, 0, 0);
#pragma unroll
    for (int r = 0; r < 4; r++) {
        int row = tm * 16 + q * 4 + r;
        int col = tn * 16 + fr;
        float v = acc[r] + dtb[col];
        v = softplusf(v);
        delta[(size_t)row * DINNER + col] = (bf16)v;
    }
}

// Stage summed x_dbl cols [cbase, cbase+ncols) for CLEN tokens into LDS.
static __device__ __forceinline__ void stage_sum(const float* __restrict__ xdblp,
                                                 int tok0, int cbase,
                                                 float* sdst, int ncols, int tid)
{
    int nth = ncols * CLEN / 4;
    if (tid < nth) {
        int per = ncols / 4;
        int l = tid / per, part = tid % per;
        f32x4 acc = (f32x4){0.f, 0.f, 0.f, 0.f};
#pragma unroll
        for (int p = 0; p < NP; p++)
            acc += *(const f32x4*)&xdblp[((size_t)p * NTOK + tok0 + l) * 64 + cbase + part * 4];
        sdst[l * ncols + part * 4 + 0] = acc[0];
        sdst[l * ncols + part * 4 + 1] = acc[1];
        sdst[l * ncols + part * 4 + 2] = acc[2];
        sdst[l * ncols + part * 4 + 3] = acc[3];
    }
}

// ---------------------------------------------------------------------------
// Chunked selective scan. An pre-scaled by log2e -> exp2f (one v_mul fewer
// per state-update than __expf; ~134M fewer v_muls across both passes).
// ---------------------------------------------------------------------------
__global__ __launch_bounds__(256) void scan_a(const bf16* __restrict__ delta,
                                              const bf16* __restrict__ uact,
                                              const float* __restrict__ xdblp,
                                              const float* __restrict__ Alog,
                                              float* __restrict__ S,
                                              float* __restrict__ sumd)
{
    const int d = blockIdx.x * 256 + threadIdx.x;
    const int chunk = blockIdx.y, b = blockIdx.z;
    const int tok0 = b * LL + chunk * CLEN;

    __shared__ float sB[CLEN][16];    // x_dbl cols [32,48) summed over partials
    stage_sum(xdblp, tok0, 32, &sB[0][0], 16, threadIdx.x);

    float An[16];   // -exp(A_log) * log2(e)
#pragma unroll
    for (int n = 0; n < 16; n += 4) {
        f32x4 v = *(const f32x4*)&Alog[(size_t)d * 16 + n];
        An[n]     = -__expf(v[0]) * LOG2E; An[n + 1] = -__expf(v[1]) * LOG2E;
        An[n + 2] = -__expf(v[2]) * LOG2E; An[n + 3] = -__expf(v[3]) * LOG2E;
    }
    bf16 dl[CLEN], uu[CLEN];
#pragma unroll
    for (int l = 0; l < CLEN; l++) {
        dl[l] = delta[(size_t)(tok0 + l) * DINNER + d];
        uu[l] = uact [(size_t)(tok0 + l) * DINNER + d];
    }
    __syncthreads();

    float h[16];
#pragma unroll
    for (int n = 0; n < 16; n++) h[n] = 0.f;
    float sd = 0.f;
#pragma unroll
    for (int l = 0; l < CLEN; l++) {
        float dc = (float)dl[l];
        float du = dc * (float)uu[l];
        sd += dc;
#pragma unroll
        for (int n = 0; n < 16; n++) {
            float dA = exp2f(dc * An[n]);
            h[n] = dA * h[n] + du * sB[l][n];
        }
    }
    size_t base = (((size_t)(b * NCHUNK + chunk)) << 14) + (size_t)d * 16;
#pragma unroll
    for (int n = 0; n < 16; n += 4)
        *(f32x4*)&S[base + n] = (f32x4){h[n], h[n + 1], h[n + 2], h[n + 3]};
    sumd[(b * NCHUNK + chunk) * DINNER + d] = sd;
}

// Pass B: serial over chunks; P = exp2(An2 * sumdelta). IN-PLACE entry states.
__global__ __launch_bounds__(256) void scan_b(float* __restrict__ S,
                                              const float* __restrict__ sumd,
                                              const float* __restrict__ Alog)
{
    int idx = blockIdx.x * 256 + threadIdx.x;   // BB * DINNER * DSTATE
    int b = idx >> 14, dn = idx & 16383;
    int d = dn >> 4;
    float An = -__expf(Alog[dn]) * LOG2E;       // dn == d*16+n
    float hc = 0.f;
#pragma unroll
    for (int c = 0; c < NCHUNK; c++) {
        size_t o = (((size_t)(b * NCHUNK + c)) << 14) + dn;
        float s_loc = S[o];
        float P = exp2f(An * sumd[(b * NCHUNK + c) * DINNER + d]);
        S[o] = hc;
        hc = P * hc + s_loc;
    }
}

// Pass C: re-scan with entry state; y = C.h + u*D, gate silu(z).
// xz: z read from cols [1024,2048), yg written into dead u-cols [0,1024).
__global__ __launch_bounds__(256) void scan_c(const bf16* __restrict__ delta,
                                              const bf16* __restrict__ uact,
                                              const float* __restrict__ xdblp,
                                              const float* __restrict__ Alog,
                                              const float* __restrict__ Hent,
                                              bf16* xz,
                                              const float* __restrict__ Dvec)
{
    const int d = blockIdx.x * 256 + threadIdx.x;
    const int chunk = blockIdx.y, b = blockIdx.z;
    const int tok0 = b * LL + chunk * CLEN;

    __shared__ float sBC[CLEN][32];   // x_dbl cols [32,64) summed over partials
    stage_sum(xdblp, tok0, 32, &sBC[0][0], 32, threadIdx.x);

    float An[16];
#pragma unroll
    for (int n = 0; n < 16; n += 4) {
        f32x4 v = *(const f32x4*)&Alog[(size_t)d * 16 + n];
        An[n]     = -__expf(v[0]) * LOG2E; An[n + 1] = -__expf(v[1]) * LOG2E;
        An[n + 2] = -__expf(v[2]) * LOG2E; An[n + 3] = -__expf(v[3]) * LOG2E;
    }
    bf16 dl[CLEN], uu[CLEN], zz[CLEN];
#pragma unroll
    for (int l = 0; l < CLEN; l++) {
        dl[l] = delta[(size_t)(tok0 + l) * DINNER + d];
        uu[l] = uact [(size_t)(tok0 + l) * DINNER + d];
        zz[l] = xz[(size_t)(tok0 + l) * (2 * DINNER) + DINNER + d];
    }
    float h[16];
    size_t hbase = (((size_t)(b * NCHUNK + chunk)) << 14) + (size_t)d * 16;
#pragma unroll
    for (int n = 0; n < 16; n += 4) {
        f32x4 t = *(const f32x4*)&Hent[hbase + n];
        h[n] = t[0]; h[n + 1] = t[1]; h[n + 2] = t[2]; h[n + 3] = t[3];
    }
    float Dv = Dvec[d];
    __syncthreads();

#pragma unroll
    for (int l = 0; l < CLEN; l++) {
        float dc = (float)dl[l];
        float u  = (float)uu[l];
        float z  = (float)zz[l];
        float du = dc * u;
        float y = 0.f;
#pragma unroll
        for (int n = 0; n < 16; n++) {
            float dA = exp2f(dc * An[n]);
            h[n] = dA * h[n] + du * sBC[l][n];
            y += h[n] * sBC[l][16 + n];
        }
        float sz = z / (1.f + __expf(-z));
        xz[(size_t)(tok0 + l) * (2 * DINNER) + d] = (bf16)((y + u * Dv) * sz);
    }
}

// ---------------------------------------------------------------------------
extern "C" void kernel_launch(void* const* d_in, const int* in_sizes, int n_in,
                              void* d_out, int out_size, void* d_ws, size_t ws_size,
                              hipStream_t stream)
{
    const int sh = (n_in >= 13) ? 0 : -1;   // tolerate dropped bool mask
    const float* x     = (const float*)d_in[0];
    const float* gamma = (const float*)d_in[2 + sh];
    const float* beta  = (const float*)d_in[3 + sh];
    const float* win   = (const float*)d_in[4 + sh];
    const float* cw    = (const float*)d_in[5 + sh];
    const float* cb    = (const float*)d_in[6 + sh];
    const float* wx    = (const float*)d_in[7 + sh];
    const float* wdt   = (const float*)d_in[8 + sh];
    const float* bdt   = (const float*)d_in[9 + sh];
    const float* alog  = (const float*)d_in[10 + sh];
    const float* Dv    = (const float*)d_in[11 + sh];
    const float* wout  = (const float*)d_in[12 + sh];

    char* ws = (char*)d_ws;
    // Memory map (~51.2 MB of 256 MiB ws):
    //   [0,4)MB    : h (LN out) -> [0,8)MB delta after gemm_in (h dead)
    //   [8,24)MB   : xz ; yg written in-place into u-columns by scan_c
    //   [24,32)MB  : uact
    //   [32,40)MB  : xdblp fp32 partials [NP][NTOK][64]
    //   [40,48)MB  : S (entry states in-place after scan_b)
    //   [48,51.2)MB: bf16 weight shadow (win | wx | wout)
    //   sumdelta (512 KB fp32) lives in d_out (dead before out_proj).
    bf16*  h     = (bf16*)(ws);
    bf16*  delta = (bf16*)(ws);
    bf16*  xz    = (bf16*)(ws + (8u  << 20));
    bf16*  uact  = (bf16*)(ws + (24u << 20));
    float* xdblp = (float*)(ws + (32u << 20));
    float* S     = (float*)(ws + (40u << 20));
    bf16*  wb    = (bf16*)(ws + (48u << 20));
    float* sumd  = (float*)d_out;

    const bf16* win_b  = wb;
    const bf16* wx_b   = wb + WIN_N;
    const bf16* wout_b = wb + WIN_N + WX_N;

    // 1. weight cvt + LayerNorm
    prep_kernel<<<WCVT_BLOCKS + LN_BLOCKS, 256, 0, stream>>>(
        win, wx, wout, wb, x, gamma, beta, h);

    // 2. in_proj: [4096,512] x [2048,512]^T -> xz [4096,2048] bf16
    gemm_kernel<128, 128, 4, 4, 0><<<dim3(16, 32, 1), 256, 0, stream>>>(
        h, DIM, win_b, DIM, xz, nullptr, NTOK, 2 * DINNER, DIM, 0, DIM);

    // 3. conv + SiLU (2048 blocks, bf16x8)
    conv_kernel<<<(NTOK * (DINNER / 8)) / 256, 256, 0, stream>>>(xz, cw, cb, uact);

    // 4. x_proj: K-split 8, direct fp32 partial stores (512 blocks)
    gemm_kernel<64, 64, 2, 2, 1><<<dim3(1, 64, NP), 256, 0, stream>>>(
        uact, DINNER, wx_b, DINNER, xdblp, nullptr, NTOK, 64, DINNER, 0, DINNER / NP);

    // 5. delta (MFMA, 4096 blocks)
    delta_kernel<<<(NTOK / 16) * (DINNER / 16) / 4, 256, 0, stream>>>(xdblp, wdt, bdt, delta);

    // 6-8. chunked scan
    scan_a<<<dim3(4, NCHUNK, BB), 256, 0, stream>>>(delta, uact, xdblp, alog, S, sumd);
    scan_b<<<(BB * DINNER * DSTATE) / 256, 256, 0, stream>>>(S, sumd, alog);
    scan_c<<<dim3(4, NCHUNK, BB), 256, 0, stream>>>(delta, uact, xdblp, alog, S, xz, Dv);

    // 9. out_proj + residual -> d_out fp32 (512 blocks, 2/CU)
    gemm_kernel<64, 64, 2, 2, 2><<<dim3(8, 64, 1), 256, 0, stream>>>(
        xz, 2 * DINNER, wout_b, DINNER, d_out, x, NTOK, DIM, DINNER, 0, DINNER);
}

// Round 13
// 233.266 us; speedup vs baseline: 1.0019x; 1.0019x over previous
//
#include <hip/hip_runtime.h>
#include <stdint.h>

// ---- problem constants ----
#define DIM    512
#define DSTATE 16
#define DINNER 1024
#define DTRANK 32
#define BB     2
#define LL     2048
#define NTOK   (BB*LL)      // 4096
#define NCHUNK 64
#define CLEN   (LL/NCHUNK)  // 32
#define NP     8            // x_proj K-split partials
#define LOG2E  1.4426950408889634f

typedef __bf16 bf16;
typedef bf16  bf16x8 __attribute__((ext_vector_type(8)));
typedef bf16  bf16x2 __attribute__((ext_vector_type(2)));
typedef float f32x4  __attribute__((ext_vector_type(4)));

// I/O dtype: FP32 (proven r3..r12). Internals: bf16.
// Perf ledger: r11=222.1 best; r12 ping-pong dbuf REGRESSED to 233.7 (compiler
// drains vmcnt(0) at every barrier -> no overlap, 2x LDS; the guide's
// "common mistake #5"). This round: exact r11 GEMM + exp2 scans only.

static __device__ __forceinline__ bf16x8 cvt8(const float* p)
{
    f32x4 a = *(const f32x4*)p, b = *(const f32x4*)(p + 4);
    bf16x8 o;
#pragma unroll
    for (int i = 0; i < 4; i++) { o[i] = (bf16)a[i]; o[4 + i] = (bf16)b[i]; }
    return o;
}

// async global->LDS, 16B per lane; LDS dest = wave-uniform base + lane*16 [m97]
static __device__ __forceinline__ void gload_lds16(const bf16* g, bf16* l)
{
    __builtin_amdgcn_global_load_lds(
        (const __attribute__((address_space(1))) void*)g,
        (__attribute__((address_space(3))) void*)l, 16, 0, 0);
}

// ---- bf16 weight shadow ----
#define WIN_N  (2*DINNER*DIM)          // 1,048,576
#define WX_N   (64*DINNER)             // 65,536
#define WOUT_N (DIM*DINNER)            // 524,288
#define WCVT_BLOCKS 800                // (WIN_N+WX_N+WOUT_N)/(256*8)
#define LN_BLOCKS   (NTOK/4)           // 1024

// ---------------------------------------------------------------------------
// prep: [0,800) weight cvt | [800,1824) LayerNorm
// ---------------------------------------------------------------------------
__global__ __launch_bounds__(256) void prep_kernel(const float* __restrict__ win,
                                                   const float* __restrict__ wx,
                                                   const float* __restrict__ wout,
                                                   bf16* __restrict__ wb,
                                                   const float* __restrict__ x,
                                                   const float* __restrict__ gamma,
                                                   const float* __restrict__ beta,
                                                   bf16* __restrict__ h)
{
    if (blockIdx.x < WCVT_BLOCKS) {
        int i = (blockIdx.x * 256 + threadIdx.x) * 8;
        const float* s; int j; bf16* dpt;
        if      (i < WIN_N)        { s = win;  j = i;                 dpt = wb; }
        else if (i < WIN_N + WX_N) { s = wx;   j = i - WIN_N;         dpt = wb + WIN_N; }
        else                       { s = wout; j = i - WIN_N - WX_N;  dpt = wb + WIN_N + WX_N; }
        *(bf16x8*)&dpt[j] = cvt8(&s[j]);
        return;
    }
    int bid = blockIdx.x - WCVT_BLOCKS;
    int w = threadIdx.x >> 6, lane = threadIdx.x & 63;
    int token = bid * 4 + w;
    const float* xr = x + (size_t)token * DIM + lane * 8;
    f32x4 va = *(const f32x4*)xr, vb = *(const f32x4*)(xr + 4);
    float vals[8];
#pragma unroll
    for (int i = 0; i < 4; i++) { vals[i] = va[i]; vals[4 + i] = vb[i]; }
    float s = 0.f;
#pragma unroll
    for (int i = 0; i < 8; i++) s += vals[i];
#pragma unroll
    for (int off = 32; off > 0; off >>= 1) s += __shfl_xor(s, off);
    float mean = s * (1.f / DIM);
    float vs = 0.f;
#pragma unroll
    for (int i = 0; i < 8; i++) { float d = vals[i] - mean; vs += d * d; }
#pragma unroll
    for (int off = 32; off > 0; off >>= 1) vs += __shfl_xor(vs, off);
    float rstd = rsqrtf(vs * (1.f / DIM) + 1e-5f);
    f32x4 ga = *(const f32x4*)(gamma + lane * 8), gb = *(const f32x4*)(gamma + lane * 8 + 4);
    f32x4 ba = *(const f32x4*)(beta + lane * 8),  bb = *(const f32x4*)(beta + lane * 8 + 4);
    bf16x8 o;
#pragma unroll
    for (int i = 0; i < 4; i++) {
        o[i]     = (bf16)((vals[i]     - mean) * rstd * ga[i] + ba[i]);
        o[4 + i] = (bf16)((vals[4 + i] - mean) * rstd * gb[i] + bb[i]);
    }
    *(bf16x8*)(h + (size_t)token * DIM + lane * 8) = o;
}

// ---------------------------------------------------------------------------
// Tiled MFMA GEMM, single-buffer 2-barrier global_load_lds staging (r11 proven;
// r12 ping-pong dbuf regressed -- vmcnt(0) drain at every barrier kills overlap).
// C[M,N] = A[M,K(lda)] * W[N,K(ldb)]^T.
// EPI: 0 = store bf16, 1 = fp32 partial store Cout[z][M][N], 2 = fp32 resid+store
// ---------------------------------------------------------------------------
template<int BM, int BN, int TM, int TN, int EPI>
__global__ __launch_bounds__(256) void gemm_kernel(const bf16* __restrict__ A, int lda,
                                                   const bf16* __restrict__ Bw, int ldb,
                                                   void* __restrict__ Cout,
                                                   const float* __restrict__ resid,
                                                   int M, int N, int K,
                                                   int kStart, int kLen)
{
    constexpr int WCols = BN / (TN * 16);
    constexpr int WRows = 4 / WCols;
    static_assert(WRows * TM * 16 == BM, "tile mismatch");
    __shared__ __align__(16) bf16 lsA[BM * 32];
    __shared__ __align__(16) bf16 lsB[BN * 32];
    const int tid  = threadIdx.x;
    const int lane = tid & 63;
    const int w    = tid >> 6;
    const int wr = w / WCols, wc = w % WCols;
    const int fr = lane & 15, q = lane >> 4;
    const int m0 = blockIdx.y * BM, n0 = blockIdx.x * BN;
    const int ks = kStart + blockIdx.z * kLen;

    f32x4 acc[TM][TN];
#pragma unroll
    for (int i = 0; i < TM; i++)
#pragma unroll
        for (int j = 0; j < TN; j++) acc[i][j] = (f32x4){0.f, 0.f, 0.f, 0.f};

    constexpr int NCA = (BM * 4) / 256;
    constexpr int NCB = (BN * 4) / 256;

    for (int k0 = ks; k0 < ks + kLen; k0 += 32) {
        __syncthreads();
#pragma unroll
        for (int c = 0; c < NCA; c++) {
            int lin = tid + c * 256;
            gload_lds16(&A[(size_t)(m0 + (lin >> 2)) * lda + k0 + (lin & 3) * 8], &lsA[lin * 8]);
        }
#pragma unroll
        for (int c = 0; c < NCB; c++) {
            int lin = tid + c * 256;
            gload_lds16(&Bw[(size_t)(n0 + (lin >> 2)) * ldb + k0 + (lin & 3) * 8], &lsB[lin * 8]);
        }
        __syncthreads();
        bf16x8 af[TM], bfr[TN];
#pragma unroll
        for (int i = 0; i < TM; i++)
            af[i] = *(const bf16x8*)&lsA[(wr * TM * 16 + i * 16 + fr) * 32 + q * 8];
#pragma unroll
        for (int j = 0; j < TN; j++)
            bfr[j] = *(const bf16x8*)&lsB[(wc * TN * 16 + j * 16 + fr) * 32 + q * 8];
#pragma unroll
        for (int i = 0; i < TM; i++)
#pragma unroll
            for (int j = 0; j < TN; j++)
                acc[i][j] = __builtin_amdgcn_mfma_f32_16x16x32_bf16(af[i], bfr[j], acc[i][j], 0, 0, 0);
    }

    // epilogue: D[m][n] -> col = lane&15, row = (lane>>4)*4 + r  [m89/m91]
#pragma unroll
    for (int i = 0; i < TM; i++) {
#pragma unroll
        for (int j = 0; j < TN; j++) {
#pragma unroll
            for (int r = 0; r < 4; r++) {
                int row = m0 + wr * TM * 16 + i * 16 + q * 4 + r;
                int col = n0 + wc * TN * 16 + j * 16 + fr;
                float v = acc[i][j][r];
                if (EPI == 0) {
                    ((bf16*)Cout)[(size_t)row * N + col] = (bf16)v;
                } else if (EPI == 1) {
                    ((float*)Cout)[((size_t)blockIdx.z * M + row) * N + col] = v;
                } else {
                    size_t idx = (size_t)row * N + col;
                    ((float*)Cout)[idx] = resid[idx] + v;
                }
            }
        }
    }
}

// ---------------------------------------------------------------------------
// Depthwise causal conv (taps=4) + bias + SiLU. 8 channels/thread, bf16x8 I/O.
// ---------------------------------------------------------------------------
__global__ __launch_bounds__(256) void conv_kernel(const bf16* __restrict__ xz,
                                                   const float* __restrict__ cw,
                                                   const float* __restrict__ cb,
                                                   bf16* __restrict__ uact)
{
    int idx = blockIdx.x * 256 + threadIdx.x;   // NTOK * 128
    int c   = (idx & 127) * 8;
    int tok = idx >> 7;
    int b = tok >> 11, l = tok & 2047;
    float a[8];
    {
        f32x4 c0 = *(const f32x4*)&cb[c], c1 = *(const f32x4*)&cb[c + 4];
#pragma unroll
        for (int j = 0; j < 4; j++) { a[j] = c0[j]; a[4 + j] = c1[j]; }
    }
    float wv[8][4];
#pragma unroll
    for (int j = 0; j < 8; j++) {
        f32x4 wq = *(const f32x4*)&cw[(c + j) * 4];
#pragma unroll
        for (int k = 0; k < 4; k++) wv[j][k] = wq[k];
    }
#pragma unroll
    for (int k = 0; k < 4; k++) {
        int ls = l - 3 + k;
        if (ls >= 0) {
            bf16x8 uv = *(const bf16x8*)&xz[((size_t)(b * LL + ls)) * (2 * DINNER) + c];
#pragma unroll
            for (int j = 0; j < 8; j++) a[j] += (float)uv[j] * wv[j][k];
        }
    }
    bf16x8 o;
#pragma unroll
    for (int j = 0; j < 8; j++) {
        float v = a[j] / (1.f + __expf(-a[j]));
        o[j] = (bf16)v;
    }
    *(bf16x8*)&uact[(size_t)tok * DINNER + c] = o;
}

static __device__ __forceinline__ float softplusf(float v)
{
    return (v > 20.f) ? v : __logf(1.f + __expf(v));
}

// ---------------------------------------------------------------------------
// delta = softplus(dt @ dt_proj_w^T + b): one 16x16x32 MFMA per wave (K=32).
// A-fragment = sum of NP x_dbl partials (fp32), converted to bf16.
// ---------------------------------------------------------------------------
__global__ __launch_bounds__(256) void delta_kernel(const float* __restrict__ xdblp,
                                                    const float* __restrict__ dtw,
                                                    const float* __restrict__ dtb,
                                                    bf16* __restrict__ delta)
{
    int w = threadIdx.x >> 6, lane = threadIdx.x & 63;
    int tile = blockIdx.x * 4 + w;      // 256 x 64 tiles
    int tm = tile >> 6, tn = tile & 63;
    int fr = lane & 15, q = lane >> 4;
    int row_a = tm * 16 + fr;
    f32x4 s0 = (f32x4){0.f, 0.f, 0.f, 0.f}, s1 = s0;
#pragma unroll
    for (int p = 0; p < NP; p++) {
        const float* rp = &xdblp[((size_t)p * NTOK + row_a) * 64 + q * 8];
        s0 += *(const f32x4*)rp;
        s1 += *(const f32x4*)(rp + 4);
    }
    bf16x8 a;
#pragma unroll
    for (int i = 0; i < 4; i++) { a[i] = (bf16)s0[i]; a[4 + i] = (bf16)s1[i]; }
    bf16x8 b = cvt8(&dtw[(size_t)(tn * 16 + fr) * 32 + q * 8]);
    f32x4 acc = (f32x4){0.f, 0.f, 0.f, 0.f};
    acc = __builtin_amdgcn_mfma_f32_16x16x32_bf16(a, b, acc, 0, 0, 0);
#pragma unroll
    for (int r = 0; r < 4; r++) {
        int row = tm * 16 + q * 4 + r;
        int col = tn * 16 + fr;
        float v = acc[r] + dtb[col];
        v = softplusf(v);
        delta[(size_t)row * DINNER + col] = (bf16)v;
    }
}

// Stage summed x_dbl cols [cbase, cbase+ncols) for CLEN tokens into LDS.
static __device__ __forceinline__ void stage_sum(const float* __restrict__ xdblp,
                                                 int tok0, int cbase,
                                                 float* sdst, int ncols, int tid)
{
    int nth = ncols * CLEN / 4;
    if (tid < nth) {
        int per = ncols / 4;
        int l = tid / per, part = tid % per;
        f32x4 acc = (f32x4){0.f, 0.f, 0.f, 0.f};
#pragma unroll
        for (int p = 0; p < NP; p++)
            acc += *(const f32x4*)&xdblp[((size_t)p * NTOK + tok0 + l) * 64 + cbase + part * 4];
        sdst[l * ncols + part * 4 + 0] = acc[0];
        sdst[l * ncols + part * 4 + 1] = acc[1];
        sdst[l * ncols + part * 4 + 2] = acc[2];
        sdst[l * ncols + part * 4 + 3] = acc[3];
    }
}

// ---------------------------------------------------------------------------
// Chunked selective scan. An pre-scaled by log2e -> exp2f (one fewer v_mul
// per state-update than __expf).
// ---------------------------------------------------------------------------
__global__ __launch_bounds__(256) void scan_a(const bf16* __restrict__ delta,
                                              const bf16* __restrict__ uact,
                                              const float* __restrict__ xdblp,
                                              const float* __restrict__ Alog,
                                              float* __restrict__ S,
                                              float* __restrict__ sumd)
{
    const int d = blockIdx.x * 256 + threadIdx.x;
    const int chunk = blockIdx.y, b = blockIdx.z;
    const int tok0 = b * LL + chunk * CLEN;

    __shared__ float sB[CLEN][16];    // x_dbl cols [32,48) summed over partials
    stage_sum(xdblp, tok0, 32, &sB[0][0], 16, threadIdx.x);

    float An[16];   // -exp(A_log) * log2(e)
#pragma unroll
    for (int n = 0; n < 16; n += 4) {
        f32x4 v = *(const f32x4*)&Alog[(size_t)d * 16 + n];
        An[n]     = -__expf(v[0]) * LOG2E; An[n + 1] = -__expf(v[1]) * LOG2E;
        An[n + 2] = -__expf(v[2]) * LOG2E; An[n + 3] = -__expf(v[3]) * LOG2E;
    }
    bf16 dl[CLEN], uu[CLEN];
#pragma unroll
    for (int l = 0; l < CLEN; l++) {
        dl[l] = delta[(size_t)(tok0 + l) * DINNER + d];
        uu[l] = uact [(size_t)(tok0 + l) * DINNER + d];
    }
    __syncthreads();

    float h[16];
#pragma unroll
    for (int n = 0; n < 16; n++) h[n] = 0.f;
    float sd = 0.f;
#pragma unroll
    for (int l = 0; l < CLEN; l++) {
        float dc = (float)dl[l];
        float du = dc * (float)uu[l];
        sd += dc;
#pragma unroll
        for (int n = 0; n < 16; n++) {
            float dA = exp2f(dc * An[n]);
            h[n] = dA * h[n] + du * sB[l][n];
        }
    }
    size_t base = (((size_t)(b * NCHUNK + chunk)) << 14) + (size_t)d * 16;
#pragma unroll
    for (int n = 0; n < 16; n += 4)
        *(f32x4*)&S[base + n] = (f32x4){h[n], h[n + 1], h[n + 2], h[n + 3]};
    sumd[(b * NCHUNK + chunk) * DINNER + d] = sd;
}

// Pass B: serial over chunks; P = exp2(An * sumdelta). IN-PLACE entry states.
__global__ __launch_bounds__(256) void scan_b(float* __restrict__ S,
                                              const float* __restrict__ sumd,
                                              const float* __restrict__ Alog)
{
    int idx = blockIdx.x * 256 + threadIdx.x;   // BB * DINNER * DSTATE
    int b = idx >> 14, dn = idx & 16383;
    int d = dn >> 4;
    float An = -__expf(Alog[dn]) * LOG2E;       // dn == d*16+n
    float hc = 0.f;
#pragma unroll
    for (int c = 0; c < NCHUNK; c++) {
        size_t o = (((size_t)(b * NCHUNK + c)) << 14) + dn;
        float s_loc = S[o];
        float P = exp2f(An * sumd[(b * NCHUNK + c) * DINNER + d]);
        S[o] = hc;
        hc = P * hc + s_loc;
    }
}

// Pass C: re-scan with entry state; y = C.h + u*D, gate silu(z).
// xz: z read from cols [1024,2048), yg written into dead u-cols [0,1024).
__global__ __launch_bounds__(256) void scan_c(const bf16* __restrict__ delta,
                                              const bf16* __restrict__ uact,
                                              const float* __restrict__ xdblp,
                                              const float* __restrict__ Alog,
                                              const float* __restrict__ Hent,
                                              bf16* xz,
                                              const float* __restrict__ Dvec)
{
    const int d = blockIdx.x * 256 + threadIdx.x;
    const int chunk = blockIdx.y, b = blockIdx.z;
    const int tok0 = b * LL + chunk * CLEN;

    __shared__ float sBC[CLEN][32];   // x_dbl cols [32,64) summed over partials
    stage_sum(xdblp, tok0, 32, &sBC[0][0], 32, threadIdx.x);

    float An[16];
#pragma unroll
    for (int n = 0; n < 16; n += 4) {
        f32x4 v = *(const f32x4*)&Alog[(size_t)d * 16 + n];
        An[n]     = -__expf(v[0]) * LOG2E; An[n + 1] = -__expf(v[1]) * LOG2E;
        An[n + 2] = -__expf(v[2]) * LOG2E; An[n + 3] = -__expf(v[3]) * LOG2E;
    }
    bf16 dl[CLEN], uu[CLEN], zz[CLEN];
#pragma unroll
    for (int l = 0; l < CLEN; l++) {
        dl[l] = delta[(size_t)(tok0 + l) * DINNER + d];
        uu[l] = uact [(size_t)(tok0 + l) * DINNER + d];
        zz[l] = xz[(size_t)(tok0 + l) * (2 * DINNER) + DINNER + d];
    }
    float h[16];
    size_t hbase = (((size_t)(b * NCHUNK + chunk)) << 14) + (size_t)d * 16;
#pragma unroll
    for (int n = 0; n < 16; n += 4) {
        f32x4 t = *(const f32x4*)&Hent[hbase + n];
        h[n] = t[0]; h[n + 1] = t[1]; h[n + 2] = t[2]; h[n + 3] = t[3];
    }
    float Dv = Dvec[d];
    __syncthreads();

#pragma unroll
    for (int l = 0; l < CLEN; l++) {
        float dc = (float)dl[l];
        float u  = (float)uu[l];
        float z  = (float)zz[l];
        float du = dc * u;
        float y = 0.f;
#pragma unroll
        for (int n = 0; n < 16; n++) {
            float dA = exp2f(dc * An[n]);
            h[n] = dA * h[n] + du * sBC[l][n];
            y += h[n] * sBC[l][16 + n];
        }
        float sz = z / (1.f + __expf(-z));
        xz[(size_t)(tok0 + l) * (2 * DINNER) + d] = (bf16)((y + u * Dv) * sz);
    }
}

// ---------------------------------------------------------------------------
extern "C" void kernel_launch(void* const* d_in, const int* in_sizes, int n_in,
                              void* d_out, int out_size, void* d_ws, size_t ws_size,
                              hipStream_t stream)
{
    const int sh = (n_in >= 13) ? 0 : -1;   // tolerate dropped bool mask
    const float* x     = (const float*)d_in[0];
    const float* gamma = (const float*)d_in[2 + sh];
    const float* beta  = (const float*)d_in[3 + sh];
    const float* win   = (const float*)d_in[4 + sh];
    const float* cw    = (const float*)d_in[5 + sh];
    const float* cb    = (const float*)d_in[6 + sh];
    const float* wx    = (const float*)d_in[7 + sh];
    const float* wdt   = (const float*)d_in[8 + sh];
    const float* bdt   = (const float*)d_in[9 + sh];
    const float* alog  = (const float*)d_in[10 + sh];
    const float* Dv    = (const float*)d_in[11 + sh];
    const float* wout  = (const float*)d_in[12 + sh];

    char* ws = (char*)d_ws;
    // Memory map (~51.2 MB of 256 MiB ws):
    //   [0,4)MB    : h (LN out) -> [0,8)MB delta after gemm_in (h dead)
    //   [8,24)MB   : xz ; yg written in-place into u-columns by scan_c
    //   [24,32)MB  : uact
    //   [32,40)MB  : xdblp fp32 partials [NP][NTOK][64]
    //   [40,48)MB  : S (entry states in-place after scan_b)
    //   [48,51.2)MB: bf16 weight shadow (win | wx | wout)
    //   sumdelta (512 KB fp32) lives in d_out (dead before out_proj).
    bf16*  h     = (bf16*)(ws);
    bf16*  delta = (bf16*)(ws);
    bf16*  xz    = (bf16*)(ws + (8u  << 20));
    bf16*  uact  = (bf16*)(ws + (24u << 20));
    float* xdblp = (float*)(ws + (32u << 20));
    float* S     = (float*)(ws + (40u << 20));
    bf16*  wb    = (bf16*)(ws + (48u << 20));
    float* sumd  = (float*)d_out;

    const bf16* win_b  = wb;
    const bf16* wx_b   = wb + WIN_N;
    const bf16* wout_b = wb + WIN_N + WX_N;

    // 1. weight cvt + LayerNorm
    prep_kernel<<<WCVT_BLOCKS + LN_BLOCKS, 256, 0, stream>>>(
        win, wx, wout, wb, x, gamma, beta, h);

    // 2. in_proj: [4096,512] x [2048,512]^T -> xz [4096,2048] bf16
    gemm_kernel<128, 128, 4, 4, 0><<<dim3(16, 32, 1), 256, 0, stream>>>(
        h, DIM, win_b, DIM, xz, nullptr, NTOK, 2 * DINNER, DIM, 0, DIM);

    // 3. conv + SiLU (2048 blocks, bf16x8)
    conv_kernel<<<(NTOK * (DINNER / 8)) / 256, 256, 0, stream>>>(xz, cw, cb, uact);

    // 4. x_proj: K-split 8, direct fp32 partial stores (512 blocks)
    gemm_kernel<64, 64, 2, 2, 1><<<dim3(1, 64, NP), 256, 0, stream>>>(
        uact, DINNER, wx_b, DINNER, xdblp, nullptr, NTOK, 64, DINNER, 0, DINNER / NP);

    // 5. delta (MFMA, 4096 blocks)
    delta_kernel<<<(NTOK / 16) * (DINNER / 16) / 4, 256, 0, stream>>>(xdblp, wdt, bdt, delta);

    // 6-8. chunked scan
    scan_a<<<dim3(4, NCHUNK, BB), 256, 0, stream>>>(delta, uact, xdblp, alog, S, sumd);
    scan_b<<<(BB * DINNER * DSTATE) / 256, 256, 0, stream>>>(S, sumd, alog);
    scan_c<<<dim3(4, NCHUNK, BB), 256, 0, stream>>>(delta, uact, xdblp, alog, S, xz, Dv);

    // 9. out_proj + residual -> d_out fp32 (512 blocks, 2/CU)
    gemm_kernel<64, 64, 2, 2, 2><<<dim3(8, 64, 1), 256, 0, stream>>>(
        xz, 2 * DINNER, wout_b, DINNER, d_out, x, NTOK, DIM, DINNER, 0, DINNER);
}

// Round 14
// 220.355 us; speedup vs baseline: 1.0606x; 1.0586x over previous
//
#include <hip/hip_runtime.h>
#include <stdint.h>

// ---- problem constants ----
#define DIM    512
#define DSTATE 16
#define DINNER 1024
#define DTRANK 32
#define BB     2
#define LL     2048
#define NTOK   (BB*LL)      // 4096
#define NCHUNK 64
#define CLEN   (LL/NCHUNK)  // 32
#define NP     8            // x_proj K-split partials

typedef __bf16 bf16;
typedef bf16  bf16x8 __attribute__((ext_vector_type(8)));
typedef bf16  bf16x2 __attribute__((ext_vector_type(2)));
typedef float f32x4  __attribute__((ext_vector_type(4)));

// I/O dtype: FP32 (proven r3..r13). Internals: bf16.
// Perf ledger: r11=222.1 BEST (this exact code). r12/r13 A/B isolated exp2f
// as an ~11us REGRESSION (libm exp2f takes the OCML precise path; __expf is
// the raw v_exp_f32 intrinsic). Ping-pong dbuf was ~neutral. This round:
// byte-exact r11 revert (__expf everywhere).

static __device__ __forceinline__ bf16x8 cvt8(const float* p)
{
    f32x4 a = *(const f32x4*)p, b = *(const f32x4*)(p + 4);
    bf16x8 o;
#pragma unroll
    for (int i = 0; i < 4; i++) { o[i] = (bf16)a[i]; o[4 + i] = (bf16)b[i]; }
    return o;
}

// async global->LDS, 16B per lane; LDS dest = wave-uniform base + lane*16 [m97]
static __device__ __forceinline__ void gload_lds16(const bf16* g, bf16* l)
{
    __builtin_amdgcn_global_load_lds(
        (const __attribute__((address_space(1))) void*)g,
        (__attribute__((address_space(3))) void*)l, 16, 0, 0);
}

// ---- bf16 weight shadow ----
#define WIN_N  (2*DINNER*DIM)          // 1,048,576
#define WX_N   (64*DINNER)             // 65,536
#define WOUT_N (DIM*DINNER)            // 524,288
#define WCVT_BLOCKS 800                // (WIN_N+WX_N+WOUT_N)/(256*8)
#define LN_BLOCKS   (NTOK/4)           // 1024

// ---------------------------------------------------------------------------
// prep: [0,800) weight cvt | [800,1824) LayerNorm
// ---------------------------------------------------------------------------
__global__ __launch_bounds__(256) void prep_kernel(const float* __restrict__ win,
                                                   const float* __restrict__ wx,
                                                   const float* __restrict__ wout,
                                                   bf16* __restrict__ wb,
                                                   const float* __restrict__ x,
                                                   const float* __restrict__ gamma,
                                                   const float* __restrict__ beta,
                                                   bf16* __restrict__ h)
{
    if (blockIdx.x < WCVT_BLOCKS) {
        int i = (blockIdx.x * 256 + threadIdx.x) * 8;
        const float* s; int j; bf16* dpt;
        if      (i < WIN_N)        { s = win;  j = i;                 dpt = wb; }
        else if (i < WIN_N + WX_N) { s = wx;   j = i - WIN_N;         dpt = wb + WIN_N; }
        else                       { s = wout; j = i - WIN_N - WX_N;  dpt = wb + WIN_N + WX_N; }
        *(bf16x8*)&dpt[j] = cvt8(&s[j]);
        return;
    }
    int bid = blockIdx.x - WCVT_BLOCKS;
    int w = threadIdx.x >> 6, lane = threadIdx.x & 63;
    int token = bid * 4 + w;
    const float* xr = x + (size_t)token * DIM + lane * 8;
    f32x4 va = *(const f32x4*)xr, vb = *(const f32x4*)(xr + 4);
    float vals[8];
#pragma unroll
    for (int i = 0; i < 4; i++) { vals[i] = va[i]; vals[4 + i] = vb[i]; }
    float s = 0.f;
#pragma unroll
    for (int i = 0; i < 8; i++) s += vals[i];
#pragma unroll
    for (int off = 32; off > 0; off >>= 1) s += __shfl_xor(s, off);
    float mean = s * (1.f / DIM);
    float vs = 0.f;
#pragma unroll
    for (int i = 0; i < 8; i++) { float d = vals[i] - mean; vs += d * d; }
#pragma unroll
    for (int off = 32; off > 0; off >>= 1) vs += __shfl_xor(vs, off);
    float rstd = rsqrtf(vs * (1.f / DIM) + 1e-5f);
    f32x4 ga = *(const f32x4*)(gamma + lane * 8), gb = *(const f32x4*)(gamma + lane * 8 + 4);
    f32x4 ba = *(const f32x4*)(beta + lane * 8),  bb = *(const f32x4*)(beta + lane * 8 + 4);
    bf16x8 o;
#pragma unroll
    for (int i = 0; i < 4; i++) {
        o[i]     = (bf16)((vals[i]     - mean) * rstd * ga[i] + ba[i]);
        o[4 + i] = (bf16)((vals[4 + i] - mean) * rstd * gb[i] + bb[i]);
    }
    *(bf16x8*)(h + (size_t)token * DIM + lane * 8) = o;
}

// ---------------------------------------------------------------------------
// Tiled MFMA GEMM, single-buffer 2-barrier global_load_lds staging (r11 proven).
// C[M,N] = A[M,K(lda)] * W[N,K(ldb)]^T.
// EPI: 0 = store bf16, 1 = fp32 partial store Cout[z][M][N], 2 = fp32 resid+store
// ---------------------------------------------------------------------------
template<int BM, int BN, int TM, int TN, int EPI>
__global__ __launch_bounds__(256) void gemm_kernel(const bf16* __restrict__ A, int lda,
                                                   const bf16* __restrict__ Bw, int ldb,
                                                   void* __restrict__ Cout,
                                                   const float* __restrict__ resid,
                                                   int M, int N, int K,
                                                   int kStart, int kLen)
{
    constexpr int WCols = BN / (TN * 16);
    constexpr int WRows = 4 / WCols;
    static_assert(WRows * TM * 16 == BM, "tile mismatch");
    __shared__ __align__(16) bf16 lsA[BM * 32];
    __shared__ __align__(16) bf16 lsB[BN * 32];
    const int tid  = threadIdx.x;
    const int lane = tid & 63;
    const int w    = tid >> 6;
    const int wr = w / WCols, wc = w % WCols;
    const int fr = lane & 15, q = lane >> 4;
    const int m0 = blockIdx.y * BM, n0 = blockIdx.x * BN;
    const int ks = kStart + blockIdx.z * kLen;

    f32x4 acc[TM][TN];
#pragma unroll
    for (int i = 0; i < TM; i++)
#pragma unroll
        for (int j = 0; j < TN; j++) acc[i][j] = (f32x4){0.f, 0.f, 0.f, 0.f};

    constexpr int NCA = (BM * 4) / 256;
    constexpr int NCB = (BN * 4) / 256;

    for (int k0 = ks; k0 < ks + kLen; k0 += 32) {
        __syncthreads();
#pragma unroll
        for (int c = 0; c < NCA; c++) {
            int lin = tid + c * 256;
            gload_lds16(&A[(size_t)(m0 + (lin >> 2)) * lda + k0 + (lin & 3) * 8], &lsA[lin * 8]);
        }
#pragma unroll
        for (int c = 0; c < NCB; c++) {
            int lin = tid + c * 256;
            gload_lds16(&Bw[(size_t)(n0 + (lin >> 2)) * ldb + k0 + (lin & 3) * 8], &lsB[lin * 8]);
        }
        __syncthreads();
        bf16x8 af[TM], bfr[TN];
#pragma unroll
        for (int i = 0; i < TM; i++)
            af[i] = *(const bf16x8*)&lsA[(wr * TM * 16 + i * 16 + fr) * 32 + q * 8];
#pragma unroll
        for (int j = 0; j < TN; j++)
            bfr[j] = *(const bf16x8*)&lsB[(wc * TN * 16 + j * 16 + fr) * 32 + q * 8];
#pragma unroll
        for (int i = 0; i < TM; i++)
#pragma unroll
            for (int j = 0; j < TN; j++)
                acc[i][j] = __builtin_amdgcn_mfma_f32_16x16x32_bf16(af[i], bfr[j], acc[i][j], 0, 0, 0);
    }

    // epilogue: D[m][n] -> col = lane&15, row = (lane>>4)*4 + r  [m89/m91]
#pragma unroll
    for (int i = 0; i < TM; i++) {
#pragma unroll
        for (int j = 0; j < TN; j++) {
#pragma unroll
            for (int r = 0; r < 4; r++) {
                int row = m0 + wr * TM * 16 + i * 16 + q * 4 + r;
                int col = n0 + wc * TN * 16 + j * 16 + fr;
                float v = acc[i][j][r];
                if (EPI == 0) {
                    ((bf16*)Cout)[(size_t)row * N + col] = (bf16)v;
                } else if (EPI == 1) {
                    ((float*)Cout)[((size_t)blockIdx.z * M + row) * N + col] = v;
                } else {
                    size_t idx = (size_t)row * N + col;
                    ((float*)Cout)[idx] = resid[idx] + v;
                }
            }
        }
    }
}

// ---------------------------------------------------------------------------
// Depthwise causal conv (taps=4) + bias + SiLU. 8 channels/thread, bf16x8 I/O.
// ---------------------------------------------------------------------------
__global__ __launch_bounds__(256) void conv_kernel(const bf16* __restrict__ xz,
                                                   const float* __restrict__ cw,
                                                   const float* __restrict__ cb,
                                                   bf16* __restrict__ uact)
{
    int idx = blockIdx.x * 256 + threadIdx.x;   // NTOK * 128
    int c   = (idx & 127) * 8;
    int tok = idx >> 7;
    int b = tok >> 11, l = tok & 2047;
    float a[8];
    {
        f32x4 c0 = *(const f32x4*)&cb[c], c1 = *(const f32x4*)&cb[c + 4];
#pragma unroll
        for (int j = 0; j < 4; j++) { a[j] = c0[j]; a[4 + j] = c1[j]; }
    }
    float wv[8][4];
#pragma unroll
    for (int j = 0; j < 8; j++) {
        f32x4 wq = *(const f32x4*)&cw[(c + j) * 4];
#pragma unroll
        for (int k = 0; k < 4; k++) wv[j][k] = wq[k];
    }
#pragma unroll
    for (int k = 0; k < 4; k++) {
        int ls = l - 3 + k;
        if (ls >= 0) {
            bf16x8 uv = *(const bf16x8*)&xz[((size_t)(b * LL + ls)) * (2 * DINNER) + c];
#pragma unroll
            for (int j = 0; j < 8; j++) a[j] += (float)uv[j] * wv[j][k];
        }
    }
    bf16x8 o;
#pragma unroll
    for (int j = 0; j < 8; j++) {
        float v = a[j] / (1.f + __expf(-a[j]));
        o[j] = (bf16)v;
    }
    *(bf16x8*)&uact[(size_t)tok * DINNER + c] = o;
}

static __device__ __forceinline__ float softplusf(float v)
{
    return (v > 20.f) ? v : __logf(1.f + __expf(v));
}

// ---------------------------------------------------------------------------
// delta = softplus(dt @ dt_proj_w^T + b): one 16x16x32 MFMA per wave (K=32).
// A-fragment = sum of NP x_dbl partials (fp32), converted to bf16.
// ---------------------------------------------------------------------------
__global__ __launch_bounds__(256) void delta_kernel(const float* __restrict__ xdblp,
                                                    const float* __restrict__ dtw,
                                                    const float* __restrict__ dtb,
                                                    bf16* __restrict__ delta)
{
    int w = threadIdx.x >> 6, lane = threadIdx.x & 63;
    int tile = blockIdx.x * 4 + w;      // 256 x 64 tiles
    int tm = tile >> 6, tn = tile & 63;
    int fr = lane & 15, q = lane >> 4;
    int row_a = tm * 16 + fr;
    f32x4 s0 = (f32x4){0.f, 0.f, 0.f, 0.f}, s1 = s0;
#pragma unroll
    for (int p = 0; p < NP; p++) {
        const float* rp = &xdblp[((size_t)p * NTOK + row_a) * 64 + q * 8];
        s0 += *(const f32x4*)rp;
        s1 += *(const f32x4*)(rp + 4);
    }
    bf16x8 a;
#pragma unroll
    for (int i = 0; i < 4; i++) { a[i] = (bf16)s0[i]; a[4 + i] = (bf16)s1[i]; }
    bf16x8 b = cvt8(&dtw[(size_t)(tn * 16 + fr) * 32 + q * 8]);
    f32x4 acc = (f32x4){0.f, 0.f, 0.f, 0.f};
    acc = __builtin_amdgcn_mfma_f32_16x16x32_bf16(a, b, acc, 0, 0, 0);
#pragma unroll
    for (int r = 0; r < 4; r++) {
        int row = tm * 16 + q * 4 + r;
        int col = tn * 16 + fr;
        float v = acc[r] + dtb[col];
        v = softplusf(v);
        delta[(size_t)row * DINNER + col] = (bf16)v;
    }
}

// Stage summed x_dbl cols [cbase, cbase+ncols) for CLEN tokens into LDS.
static __device__ __forceinline__ void stage_sum(const float* __restrict__ xdblp,
                                                 int tok0, int cbase,
                                                 float* sdst, int ncols, int tid)
{
    int nth = ncols * CLEN / 4;
    if (tid < nth) {
        int per = ncols / 4;
        int l = tid / per, part = tid % per;
        f32x4 acc = (f32x4){0.f, 0.f, 0.f, 0.f};
#pragma unroll
        for (int p = 0; p < NP; p++)
            acc += *(const f32x4*)&xdblp[((size_t)p * NTOK + tok0 + l) * 64 + cbase + part * 4];
        sdst[l * ncols + part * 4 + 0] = acc[0];
        sdst[l * ncols + part * 4 + 1] = acc[1];
        sdst[l * ncols + part * 4 + 2] = acc[2];
        sdst[l * ncols + part * 4 + 3] = acc[3];
    }
}

// ---------------------------------------------------------------------------
// Chunked selective scan (__expf = raw v_exp_f32; exp2f regressed ~11us).
// ---------------------------------------------------------------------------
__global__ __launch_bounds__(256) void scan_a(const bf16* __restrict__ delta,
                                              const bf16* __restrict__ uact,
                                              const float* __restrict__ xdblp,
                                              const float* __restrict__ Alog,
                                              float* __restrict__ S,
                                              float* __restrict__ sumd)
{
    const int d = blockIdx.x * 256 + threadIdx.x;
    const int chunk = blockIdx.y, b = blockIdx.z;
    const int tok0 = b * LL + chunk * CLEN;

    __shared__ float sB[CLEN][16];    // x_dbl cols [32,48) summed over partials
    stage_sum(xdblp, tok0, 32, &sB[0][0], 16, threadIdx.x);

    float An[16];
#pragma unroll
    for (int n = 0; n < 16; n += 4) {
        f32x4 v = *(const f32x4*)&Alog[(size_t)d * 16 + n];
        An[n] = -__expf(v[0]); An[n + 1] = -__expf(v[1]);
        An[n + 2] = -__expf(v[2]); An[n + 3] = -__expf(v[3]);
    }
    bf16 dl[CLEN], uu[CLEN];
#pragma unroll
    for (int l = 0; l < CLEN; l++) {
        dl[l] = delta[(size_t)(tok0 + l) * DINNER + d];
        uu[l] = uact [(size_t)(tok0 + l) * DINNER + d];
    }
    __syncthreads();

    float h[16];
#pragma unroll
    for (int n = 0; n < 16; n++) h[n] = 0.f;
    float sd = 0.f;
#pragma unroll
    for (int l = 0; l < CLEN; l++) {
        float dc = (float)dl[l];
        float du = dc * (float)uu[l];
        sd += dc;
#pragma unroll
        for (int n = 0; n < 16; n++) {
            float dA = __expf(dc * An[n]);
            h[n] = dA * h[n] + du * sB[l][n];
        }
    }
    size_t base = (((size_t)(b * NCHUNK + chunk)) << 14) + (size_t)d * 16;
#pragma unroll
    for (int n = 0; n < 16; n += 4)
        *(f32x4*)&S[base + n] = (f32x4){h[n], h[n + 1], h[n + 2], h[n + 3]};
    sumd[(b * NCHUNK + chunk) * DINNER + d] = sd;
}

// Pass B: serial over chunks; P = exp(An * sumdelta). IN-PLACE entry states.
__global__ __launch_bounds__(256) void scan_b(float* __restrict__ S,
                                              const float* __restrict__ sumd,
                                              const float* __restrict__ Alog)
{
    int idx = blockIdx.x * 256 + threadIdx.x;   // BB * DINNER * DSTATE
    int b = idx >> 14, dn = idx & 16383;
    int d = dn >> 4;
    float An = -__expf(Alog[dn]);               // dn == d*16+n
    float hc = 0.f;
#pragma unroll
    for (int c = 0; c < NCHUNK; c++) {
        size_t o = (((size_t)(b * NCHUNK + c)) << 14) + dn;
        float s_loc = S[o];
        float P = __expf(An * sumd[(b * NCHUNK + c) * DINNER + d]);
        S[o] = hc;
        hc = P * hc + s_loc;
    }
}

// Pass C: re-scan with entry state; y = C.h + u*D, gate silu(z).
// xz: z read from cols [1024,2048), yg written into dead u-cols [0,1024).
__global__ __launch_bounds__(256) void scan_c(const bf16* __restrict__ delta,
                                              const bf16* __restrict__ uact,
                                              const float* __restrict__ xdblp,
                                              const float* __restrict__ Alog,
                                              const float* __restrict__ Hent,
                                              bf16* xz,
                                              const float* __restrict__ Dvec)
{
    const int d = blockIdx.x * 256 + threadIdx.x;
    const int chunk = blockIdx.y, b = blockIdx.z;
    const int tok0 = b * LL + chunk * CLEN;

    __shared__ float sBC[CLEN][32];   // x_dbl cols [32,64) summed over partials
    stage_sum(xdblp, tok0, 32, &sBC[0][0], 32, threadIdx.x);

    float An[16];
#pragma unroll
    for (int n = 0; n < 16; n += 4) {
        f32x4 v = *(const f32x4*)&Alog[(size_t)d * 16 + n];
        An[n] = -__expf(v[0]); An[n + 1] = -__expf(v[1]);
        An[n + 2] = -__expf(v[2]); An[n + 3] = -__expf(v[3]);
    }
    bf16 dl[CLEN], uu[CLEN], zz[CLEN];
#pragma unroll
    for (int l = 0; l < CLEN; l++) {
        dl[l] = delta[(size_t)(tok0 + l) * DINNER + d];
        uu[l] = uact [(size_t)(tok0 + l) * DINNER + d];
        zz[l] = xz[(size_t)(tok0 + l) * (2 * DINNER) + DINNER + d];
    }
    float h[16];
    size_t hbase = (((size_t)(b * NCHUNK + chunk)) << 14) + (size_t)d * 16;
#pragma unroll
    for (int n = 0; n < 16; n += 4) {
        f32x4 t = *(const f32x4*)&Hent[hbase + n];
        h[n] = t[0]; h[n + 1] = t[1]; h[n + 2] = t[2]; h[n + 3] = t[3];
    }
    float Dv = Dvec[d];
    __syncthreads();

#pragma unroll
    for (int l = 0; l < CLEN; l++) {
        float dc = (float)dl[l];
        float u  = (float)uu[l];
        float z  = (float)zz[l];
        float du = dc * u;
        float y = 0.f;
#pragma unroll
        for (int n = 0; n < 16; n++) {
            float dA = __expf(dc * An[n]);
            h[n] = dA * h[n] + du * sBC[l][n];
            y += h[n] * sBC[l][16 + n];
        }
        float sz = z / (1.f + __expf(-z));
        xz[(size_t)(tok0 + l) * (2 * DINNER) + d] = (bf16)((y + u * Dv) * sz);
    }
}

// ---------------------------------------------------------------------------
extern "C" void kernel_launch(void* const* d_in, const int* in_sizes, int n_in,
                              void* d_out, int out_size, void* d_ws, size_t ws_size,
                              hipStream_t stream)
{
    const int sh = (n_in >= 13) ? 0 : -1;   // tolerate dropped bool mask
    const float* x     = (const float*)d_in[0];
    const float* gamma = (const float*)d_in[2 + sh];
    const float* beta  = (const float*)d_in[3 + sh];
    const float* win   = (const float*)d_in[4 + sh];
    const float* cw    = (const float*)d_in[5 + sh];
    const float* cb    = (const float*)d_in[6 + sh];
    const float* wx    = (const float*)d_in[7 + sh];
    const float* wdt   = (const float*)d_in[8 + sh];
    const float* bdt   = (const float*)d_in[9 + sh];
    const float* alog  = (const float*)d_in[10 + sh];
    const float* Dv    = (const float*)d_in[11 + sh];
    const float* wout  = (const float*)d_in[12 + sh];

    char* ws = (char*)d_ws;
    // Memory map (~51.2 MB of 256 MiB ws):
    //   [0,4)MB    : h (LN out) -> [0,8)MB delta after gemm_in (h dead)
    //   [8,24)MB   : xz ; yg written in-place into u-columns by scan_c
    //   [24,32)MB  : uact
    //   [32,40)MB  : xdblp fp32 partials [NP][NTOK][64]
    //   [40,48)MB  : S (entry states in-place after scan_b)
    //   [48,51.2)MB: bf16 weight shadow (win | wx | wout)
    //   sumdelta (512 KB fp32) lives in d_out (dead before out_proj).
    bf16*  h     = (bf16*)(ws);
    bf16*  delta = (bf16*)(ws);
    bf16*  xz    = (bf16*)(ws + (8u  << 20));
    bf16*  uact  = (bf16*)(ws + (24u << 20));
    float* xdblp = (float*)(ws + (32u << 20));
    float* S     = (float*)(ws + (40u << 20));
    bf16*  wb    = (bf16*)(ws + (48u << 20));
    float* sumd  = (float*)d_out;

    const bf16* win_b  = wb;
    const bf16* wx_b   = wb + WIN_N;
    const bf16* wout_b = wb + WIN_N + WX_N;

    // 1. weight cvt + LayerNorm
    prep_kernel<<<WCVT_BLOCKS + LN_BLOCKS, 256, 0, stream>>>(
        win, wx, wout, wb, x, gamma, beta, h);

    // 2. in_proj: [4096,512] x [2048,512]^T -> xz [4096,2048] bf16
    gemm_kernel<128, 128, 4, 4, 0><<<dim3(16, 32, 1), 256, 0, stream>>>(
        h, DIM, win_b, DIM, xz, nullptr, NTOK, 2 * DINNER, DIM, 0, DIM);

    // 3. conv + SiLU (2048 blocks, bf16x8)
    conv_kernel<<<(NTOK * (DINNER / 8)) / 256, 256, 0, stream>>>(xz, cw, cb, uact);

    // 4. x_proj: K-split 8, direct fp32 partial stores (512 blocks)
    gemm_kernel<64, 64, 2, 2, 1><<<dim3(1, 64, NP), 256, 0, stream>>>(
        uact, DINNER, wx_b, DINNER, xdblp, nullptr, NTOK, 64, DINNER, 0, DINNER / NP);

    // 5. delta (MFMA, 4096 blocks)
    delta_kernel<<<(NTOK / 16) * (DINNER / 16) / 4, 256, 0, stream>>>(xdblp, wdt, bdt, delta);

    // 6-8. chunked scan
    scan_a<<<dim3(4, NCHUNK, BB), 256, 0, stream>>>(delta, uact, xdblp, alog, S, sumd);
    scan_b<<<(BB * DINNER * DSTATE) / 256, 256, 0, stream>>>(S, sumd, alog);
    scan_c<<<dim3(4, NCHUNK, BB), 256, 0, stream>>>(delta, uact, xdblp, alog, S, xz, Dv);

    // 9. out_proj + residual -> d_out fp32 (512 blocks, 2/CU)
    gemm_kernel<64, 64, 2, 2, 2><<<dim3(8, 64, 1), 256, 0, stream>>>(
        xz, 2 * DINNER, wout_b, DINNER, d_out, x, NTOK, DIM, DINNER, 0, DINNER);
}